// Round 8
// baseline (2062.140 us; speedup 1.0000x reference)
//
#include <hip/hip_runtime.h>

#define NSEQ 1028
#define TT   256
#define CC   64
#define HH   256
#define NKT  10               // k-tiles of 32 (8 for W_hh, 2 for W_ih)
#define AROWB 656             // bytes per A row: 320*2 + 16 pad (stride%128=16 -> ~2-way only)
#define A_BYTES (32*AROWB)    // 20992, single-buffered A tile (32 seqs)
#define SLABE 32768           // elems per kt slab: 8 waves * 8 ct * 512
#define LSTM_LDS (A_BYTES + 2*SLABE*2)   // 20992 + 131072 = 152064
#define OUTP_LDS (128*264*2 + 64*264*2)  // 101376

typedef unsigned short u16;
typedef float  f32x4 __attribute__((ext_vector_type(4)));
typedef __bf16 v8bf  __attribute__((ext_vector_type(8)));

__device__ __forceinline__ u16 f2bf(float f){
  unsigned u = __builtin_bit_cast(unsigned, f);
  u += 0x7FFFu + ((u >> 16) & 1u);
  return (u16)(u >> 16);
}
__device__ __forceinline__ float sigm(float x){
  float t = __builtin_amdgcn_exp2f(-1.4426950408889634f * x);
  return __builtin_amdgcn_rcpf(1.0f + t);
}
__device__ __forceinline__ float tanh_f(float x){
  float a = __builtin_fabsf(x);
  float t = __builtin_amdgcn_exp2f(-2.885390081777927f * a);
  float r = (1.0f - t) * __builtin_amdgcn_rcpf(1.0f + t);
  return __builtin_copysignf(r, x);
}
// MFMA with B pinned in AGPR (weight residency in accumulator file)
__device__ __forceinline__ void mfma_a(f32x4& d, v8bf a, v8bf b){
  asm("v_mfma_f32_16x16x32_bf16 %0, %1, %2, %0" : "+v"(d) : "v"(a), "a"(b));
}
// MFMA with B in arch VGPR (LDS-sourced / streamed tiles)
__device__ __forceinline__ void mfma_v(f32x4& d, v8bf a, v8bf b){
  asm("v_mfma_f32_16x16x32_bf16 %0, %1, %2, %0" : "+v"(d) : "v"(a), "v"(b));
}

// ---- pack W = [W_hh | W_ih] into per-(kt,wave,ct) MFMA B-frags, bf16
__global__ void k_pack_w(const float* __restrict__ Whh, const float* __restrict__ Wih,
                         u16* __restrict__ wpack){
  int idx = blockIdx.x*256 + threadIdx.x;
  if (idx >= NKT*SLABE) return;                 // 327680
  int j    = idx & 7;
  int lane = (idx >> 3) & 63;
  int ct   = (idx >> 9) & 7;
  int w    = (idx >> 12) & 7;
  int kt   = idx >> 15;
  int col  = (ct >> 1)*256 + w*32 + (ct & 1)*16 + (lane & 15);
  int k    = kt*32 + (lane >> 4)*8 + j;
  float v  = (k < 256) ? Whh[col*256 + k] : Wih[col*64 + (k - 256)];
  wpack[idx] = f2bf(v);
}

__global__ void k_bias(const float* __restrict__ bi, const float* __restrict__ bh,
                       float* __restrict__ bias){
  int i = blockIdx.x*256 + threadIdx.x;
  if (i < 1024) bias[i] = bi[i] + bh[i];
}

__global__ void k_wlin(const float* __restrict__ Wl, u16* __restrict__ wlin){
  int i = blockIdx.x*256 + threadIdx.x;
  if (i >= 64*264) return;
  int col = i / 264, k = i % 264;
  wlin[i] = (k < 256) ? f2bf(Wl[col*256 + k]) : (u16)0;
}

// ---- x(B,C,F,T) -> y(n,t,c) bf16, n = b*257+f
__global__ void k_ytrans(const float* __restrict__ x, u16* __restrict__ ybuf){
  __shared__ u16 tile[64][257];
  int n = blockIdx.x, b = n / 257, f = n % 257, tid = threadIdx.x;
  for (int i = tid; i < 64*256; i += 256){
    int c = i >> 8, t = i & 255;
    tile[c][t] = f2bf(x[((size_t)(b*64 + c)*257 + f)*256 + t]);
  }
  __syncthreads();
  for (int i = tid; i < 256*64; i += 256){
    int t = i >> 6, c = i & 63;
    ybuf[((size_t)n*256 + t)*64 + c] = tile[c][t];
  }
}

// ---- persistent LSTM: 33 blocks x 512 thr (8 waves), 32 seqs/block (M=32).
// Residency: kt0..2 AGPR (96/wave), kt3,4 LDS (128 KB), kt5..9 streamed (320 KB/step,
// serving 2x the work of the old M=16 layout). A-tile single-buffered, 2 barriers/step.
// h(t) stored to hbuf directly from cell registers. kt5' issued in phase 2 so the
// cell+barrier (~1.1k cyc) hides its return.
__global__ __launch_bounds__(512, 2) void k_lstm(const u16* __restrict__ wpack,
      const float* __restrict__ bias, const u16* __restrict__ ybuf,
      u16* __restrict__ hbuf){
  extern __shared__ char smem[];
  char* lA = smem;                              // [32 rows][AROWB]
  u16*  lW = (u16*)(smem + A_BYTES);            // kt3,4 slabs
  const int tid = threadIdx.x, lane = tid & 63, w = tid >> 6;   // w 0..7
  const int n0 = blockIdx.x * 32;
  const int l15 = lane & 15, q = lane >> 4;
  const int yrow = tid >> 4, ychunk = tid & 15; // y staging: 32 rows x 16 chunks(8B)

  // AGPR-resident W (kt0..2): 96 AGPR/wave, pinned by "a"-constrained uses
  v8bf wreg[3][8];
  #pragma unroll
  for (int kt = 0; kt < 3; ++kt)
    #pragma unroll
    for (int ct = 0; ct < 8; ++ct)
      wreg[kt][ct] = *(const v8bf*)(wpack + ((kt*8 + w)*8 + ct)*512 + lane*8);

  { // LDS-resident W (kt3,4)
    const uint4* src = (const uint4*)(wpack + 3*SLABE);
    uint4* dst = (uint4*)lW;
    for (int i = tid; i < (2*SLABE)/8; i += 512) dst[i] = src[i];
  }
  float biasr[8];
  #pragma unroll
  for (int ct = 0; ct < 8; ++ct)
    biasr[ct] = bias[(ct >> 1)*256 + w*32 + (ct & 1)*16 + l15];

  { // zero A (h(-1)=0)
    unsigned* z = (unsigned*)lA;
    for (int i = tid; i < A_BYTES/4; i += 512) z[i] = 0;
  }
  __syncthreads();
  { // stage y[t=0]
    uint2 v = {0u, 0u};
    if (n0 + yrow < NSEQ)
      v = *(const uint2*)(ybuf + ((size_t)(n0 + yrow)*TT + 0)*64 + ychunk*4);
    *(uint2*)(lA + yrow*AROWB + 512 + ychunk*8) = v;
  }
  f32x4 creg[4];   // [mt*2+u]
  #pragma unroll
  for (int i = 0; i < 4; ++i) creg[i] = (f32x4){0.f,0.f,0.f,0.f};
  __syncthreads();

  const u16* wp = wpack;           // opaque-refreshed (defeats LICM/CSE)

  // prologue: kt5 for t=0
  v8bf sbuf[8];
  {
    const u16* wpw0 = wp + w*4096 + lane*8;
    #pragma unroll
    for (int ct = 0; ct < 8; ++ct) sbuf[ct] = *(const v8bf*)(wpw0 + 5*SLABE + ct*512);
  }

  for (int t = 0; t < TT; ++t){
    asm("" : "+s"(wp));
    const u16* wpw = wp + w*4096 + lane*8;

    // y prefetch for t+1 (consumed in phase 2; barrier1 drain covers it)
    uint2 yv = {0u, 0u};
    if (t + 1 < TT && n0 + yrow < NSEQ)
      yv = *(const uint2*)(ybuf + ((size_t)(n0 + yrow)*TT + (t + 1))*64 + ychunk*4);

    f32x4 acc[2][8];
    #pragma unroll
    for (int mt = 0; mt < 2; ++mt)
      #pragma unroll
      for (int ct = 0; ct < 8; ++ct)
        acc[mt][ct] = (f32x4){biasr[ct], biasr[ct], biasr[ct], biasr[ct]};
    asm volatile("s_nop 1"
      : "+v"(acc[0][0]), "+v"(acc[0][1]), "+v"(acc[0][2]), "+v"(acc[0][3]),
        "+v"(acc[0][4]), "+v"(acc[0][5]), "+v"(acc[0][6]), "+v"(acc[0][7]),
        "+v"(acc[1][0]), "+v"(acc[1][1]), "+v"(acc[1][2]), "+v"(acc[1][3]),
        "+v"(acc[1][4]), "+v"(acc[1][5]), "+v"(acc[1][6]), "+v"(acc[1][7]));

    #define AFRAG(kt, mt) (*(const v8bf*)(lA + ((mt)*16 + l15)*AROWB + (kt)*64 + q*16))
    #define LFRAG(kt, ct) (*(const v8bf*)(lW + (((kt)-3)*8 + w)*4096 + (ct)*512 + lane*8))

    // resident/stream interleave: kt0, kt5(->6), kt1, kt6(->7), kt2, kt7(->8),
    //                             kt3L, kt8(->9), kt4L, kt9
    { v8bf a0 = AFRAG(0,0), a1 = AFRAG(0,1);     // kt0 (AGPR)
      #pragma unroll
      for (int ct = 0; ct < 8; ++ct){ mfma_a(acc[0][ct], a0, wreg[0][ct]);
                                      mfma_a(acc[1][ct], a1, wreg[0][ct]); } }
    { v8bf a0 = AFRAG(5,0), a1 = AFRAG(5,1);     // kt5 (stream) -> refill kt6
      #pragma unroll
      for (int ct = 0; ct < 8; ++ct){ mfma_v(acc[0][ct], a0, sbuf[ct]);
                                      mfma_v(acc[1][ct], a1, sbuf[ct]); }
      #pragma unroll
      for (int ct = 0; ct < 8; ++ct) sbuf[ct] = *(const v8bf*)(wpw + 6*SLABE + ct*512);
      __builtin_amdgcn_sched_barrier(0); }
    { v8bf a0 = AFRAG(1,0), a1 = AFRAG(1,1);     // kt1 (AGPR)
      #pragma unroll
      for (int ct = 0; ct < 8; ++ct){ mfma_a(acc[0][ct], a0, wreg[1][ct]);
                                      mfma_a(acc[1][ct], a1, wreg[1][ct]); } }
    { v8bf a0 = AFRAG(6,0), a1 = AFRAG(6,1);     // kt6 -> refill kt7
      #pragma unroll
      for (int ct = 0; ct < 8; ++ct){ mfma_v(acc[0][ct], a0, sbuf[ct]);
                                      mfma_v(acc[1][ct], a1, sbuf[ct]); }
      #pragma unroll
      for (int ct = 0; ct < 8; ++ct) sbuf[ct] = *(const v8bf*)(wpw + 7*SLABE + ct*512);
      __builtin_amdgcn_sched_barrier(0); }
    { v8bf a0 = AFRAG(2,0), a1 = AFRAG(2,1);     // kt2 (AGPR)
      #pragma unroll
      for (int ct = 0; ct < 8; ++ct){ mfma_a(acc[0][ct], a0, wreg[2][ct]);
                                      mfma_a(acc[1][ct], a1, wreg[2][ct]); } }
    { v8bf a0 = AFRAG(7,0), a1 = AFRAG(7,1);     // kt7 -> refill kt8
      #pragma unroll
      for (int ct = 0; ct < 8; ++ct){ mfma_v(acc[0][ct], a0, sbuf[ct]);
                                      mfma_v(acc[1][ct], a1, sbuf[ct]); }
      #pragma unroll
      for (int ct = 0; ct < 8; ++ct) sbuf[ct] = *(const v8bf*)(wpw + 8*SLABE + ct*512);
      __builtin_amdgcn_sched_barrier(0); }
    { v8bf a0 = AFRAG(3,0), a1 = AFRAG(3,1);     // kt3 (LDS)
      #pragma unroll
      for (int ct = 0; ct < 8; ++ct){ v8bf b = LFRAG(3,ct);
                                      mfma_v(acc[0][ct], a0, b);
                                      mfma_v(acc[1][ct], a1, b); } }
    { v8bf a0 = AFRAG(8,0), a1 = AFRAG(8,1);     // kt8 -> refill kt9
      #pragma unroll
      for (int ct = 0; ct < 8; ++ct){ mfma_v(acc[0][ct], a0, sbuf[ct]);
                                      mfma_v(acc[1][ct], a1, sbuf[ct]); }
      #pragma unroll
      for (int ct = 0; ct < 8; ++ct) sbuf[ct] = *(const v8bf*)(wpw + 9*SLABE + ct*512);
      __builtin_amdgcn_sched_barrier(0); }
    { v8bf a0 = AFRAG(4,0), a1 = AFRAG(4,1);     // kt4 (LDS)
      #pragma unroll
      for (int ct = 0; ct < 8; ++ct){ v8bf b = LFRAG(4,ct);
                                      mfma_v(acc[0][ct], a0, b);
                                      mfma_v(acc[1][ct], a1, b); } }
    { v8bf a0 = AFRAG(9,0), a1 = AFRAG(9,1);     // kt9 (last stream)
      #pragma unroll
      for (int ct = 0; ct < 8; ++ct){ mfma_v(acc[0][ct], a0, sbuf[ct]);
                                      mfma_v(acc[1][ct], a1, sbuf[ct]); } }

    // MFMA->VALU hazard guard
    asm volatile("s_nop 7\n\ts_nop 7\n\ts_nop 7"
      : "+v"(acc[0][0]), "+v"(acc[0][1]), "+v"(acc[0][2]), "+v"(acc[0][3]),
        "+v"(acc[0][4]), "+v"(acc[0][5]), "+v"(acc[0][6]), "+v"(acc[0][7]),
        "+v"(acc[1][0]), "+v"(acc[1][1]), "+v"(acc[1][2]), "+v"(acc[1][3]),
        "+v"(acc[1][4]), "+v"(acc[1][5]), "+v"(acc[1][6]), "+v"(acc[1][7]));

    __syncthreads();   // barrier1: all A reads done; y(t+1) drained

    // issue kt5 for t+1 NOW: cell + barrier2 hide its return
    asm("" : "+s"(wp));
    {
      const u16* wpw2 = wp + w*4096 + lane*8;
      #pragma unroll
      for (int ct = 0; ct < 8; ++ct) sbuf[ct] = *(const v8bf*)(wpw2 + 5*SLABE + ct*512);
      __builtin_amdgcn_sched_barrier(0);
    }

    // cell update: lane owns rows mt*16+4q+j, units w*32+u*16+l15
    #pragma unroll
    for (int mt = 0; mt < 2; ++mt){
      #pragma unroll
      for (int u = 0; u < 2; ++u){
        #pragma unroll
        for (int j = 0; j < 4; ++j){
          float xi = acc[mt][0 + u][j], xf = acc[mt][2 + u][j];
          float xg = acc[mt][4 + u][j], xo = acc[mt][6 + u][j];
          float cv = sigm(xf)*creg[mt*2 + u][j] + sigm(xi)*tanh_f(xg);
          float hv = sigm(xo)*tanh_f(cv);
          creg[mt*2 + u][j] = cv;
          int row = mt*16 + 4*q + j, colu = w*32 + u*16 + l15;
          u16 hb = f2bf(hv);
          *(u16*)(lA + row*AROWB + colu*2) = hb;            // A for t+1
          if (n0 + row < NSEQ)                               // direct writeout
            hbuf[((size_t)(n0 + row)*TT + t)*HH + colu] = hb;
        }
      }
    }
    // stage y[t+1]
    if (t + 1 < TT)
      *(uint2*)(lA + yrow*AROWB + 512 + ychunk*8) = yv;
    __syncthreads();   // barrier2: A writes + kt5' drained
  }
}

// ---- out = h @ W_lin^T + b_lin, written as (B,OUT,F,T)
__global__ __launch_bounds__(256) void k_outproj(const u16* __restrict__ hbuf,
      const u16* __restrict__ wlin, const float* __restrict__ blin,
      float* __restrict__ out){
  extern __shared__ char smem[];
  u16* sA = (u16*)smem;                 // [128][264] rows = t
  u16* sB = (u16*)(smem + 128*264*2);   // [64][264]  rows = o
  const int n = blockIdx.x, th = blockIdx.y, t0 = th*128;
  const int b = n / 257, f = n % 257;
  const int tid = threadIdx.x, lane = tid & 63, wv = tid >> 6;

  for (int i = tid; i < 128*32; i += 256){
    int r = i >> 5, part = i & 31;
    *(uint4*)(sA + r*264 + part*8) =
        *(const uint4*)(hbuf + ((size_t)n*TT + t0 + r)*HH + part*8);
  }
  for (int i = tid; i < (64*264)/2; i += 256)
    ((unsigned*)sB)[i] = ((const unsigned*)wlin)[i];
  __syncthreads();

  f32x4 acc[2][4];
  #pragma unroll
  for (int m = 0; m < 2; ++m)
    #pragma unroll
    for (int nt = 0; nt < 4; ++nt){
      float bv = blin[nt*16 + (lane & 15)];
      acc[m][nt] = (f32x4){bv, bv, bv, bv};
    }
  const int khi = (lane >> 4) * 8;
  #pragma unroll
  for (int kt = 0; kt < 8; ++kt){
    v8bf av[2];
    #pragma unroll
    for (int m = 0; m < 2; ++m){
      int mt = wv*2 + m;
      av[m] = *(const v8bf*)(sA + (mt*16 + (lane & 15))*264 + kt*32 + khi);
    }
    #pragma unroll
    for (int nt = 0; nt < 4; ++nt){
      v8bf bv = *(const v8bf*)(sB + (nt*16 + (lane & 15))*264 + kt*32 + khi);
      #pragma unroll
      for (int m = 0; m < 2; ++m)
        acc[m][nt] = __builtin_amdgcn_mfma_f32_16x16x32_bf16(av[m], bv, acc[m][nt], 0, 0, 0);
    }
  }
  #pragma unroll
  for (int m = 0; m < 2; ++m){
    int mt = wv*2 + m;
    #pragma unroll
    for (int nt = 0; nt < 4; ++nt){
      int o = nt*16 + (lane & 15);
      int tb = t0 + mt*16 + 4*(lane >> 4);
      *(f32x4*)(out + (((size_t)b*64 + o)*257 + f)*TT + tb) = acc[m][nt];
    }
  }
}

extern "C" void kernel_launch(void* const* d_in, const int* in_sizes, int n_in,
                              void* d_out, int out_size, void* d_ws, size_t ws_size,
                              hipStream_t stream) {
  const float* x   = (const float*)d_in[0];
  const float* Wih = (const float*)d_in[1];
  const float* Whh = (const float*)d_in[2];
  const float* bih = (const float*)d_in[3];
  const float* bhh = (const float*)d_in[4];
  const float* Wl  = (const float*)d_in[5];
  const float* bl  = (const float*)d_in[6];
  float* out = (float*)d_out;

  char* p = (char*)d_ws;
  u16*   wpack = (u16*)p;   p += 655360;                 // 10 slabs
  float* bias  = (float*)p; p += 4096;
  u16*   wlin  = (u16*)p;   p += 33792;
  u16*   ybuf  = (u16*)p;   p += (size_t)NSEQ*TT*CC*2;   // 33.7 MB
  u16*   hbuf  = (u16*)p;                                // 134.7 MB

  hipFuncSetAttribute((const void*)k_lstm,    hipFuncAttributeMaxDynamicSharedMemorySize, LSTM_LDS);
  hipFuncSetAttribute((const void*)k_outproj, hipFuncAttributeMaxDynamicSharedMemorySize, OUTP_LDS);

  k_pack_w <<<1280, 256, 0, stream>>>(Whh, Wih, wpack);
  k_bias   <<<4,    256, 0, stream>>>(bih, bhh, bias);
  k_wlin   <<<66,   256, 0, stream>>>(Wl, wlin);
  k_ytrans <<<1028, 256, 0, stream>>>(x, ybuf);
  k_lstm   <<<33, 512, LSTM_LDS, stream>>>(wpack, bias, ybuf, hbuf);
  k_outproj<<<dim3(1028, 2), 256, OUTP_LDS, stream>>>(hbuf, wlin, bl, out);
}

// Round 9
// 1198.604 us; speedup vs baseline: 1.7205x; 1.7205x over previous
//
#include <hip/hip_runtime.h>

#define NSEQ 1028
#define TT   256
#define CC   64
#define HH   256
#define SLABE 32768            // elems per kt slab: 8 waves * 8 ct * 512
// xg-path LSTM geometry
#define AROWX 528              // 256 k * 2B + 16 pad
#define XG_A  (16*AROWX)       // 8448 B per A buffer
#define XG_LDS (2*XG_A + 2*SLABE*2)      // 16896 + 131072 = 147968
// fallback (r7) LSTM geometry
#define AROWB 656
#define FB_LDS (2*16*AROWB + 2*SLABE*2)  // 152064
#define OUTP_LDS (128*264*2 + 64*264*2)  // 101376

typedef unsigned short u16;
typedef float  f32x4 __attribute__((ext_vector_type(4)));
typedef __bf16 v8bf  __attribute__((ext_vector_type(8)));

__device__ __forceinline__ u16 f2bf(float f){
  unsigned u = __builtin_bit_cast(unsigned, f);
  u += 0x7FFFu + ((u >> 16) & 1u);
  return (u16)(u >> 16);
}
__device__ __forceinline__ float sigm(float x){
  float t = __builtin_amdgcn_exp2f(-1.4426950408889634f * x);
  return __builtin_amdgcn_rcpf(1.0f + t);
}
__device__ __forceinline__ float tanh_f(float x){
  float a = __builtin_fabsf(x);
  float t = __builtin_amdgcn_exp2f(-2.885390081777927f * a);
  float r = (1.0f - t) * __builtin_amdgcn_rcpf(1.0f + t);
  return __builtin_copysignf(r, x);
}
__device__ __forceinline__ void mfma_a(f32x4& d, v8bf a, v8bf b){
  asm("v_mfma_f32_16x16x32_bf16 %0, %1, %2, %0" : "+v"(d) : "v"(a), "a"(b));
}
__device__ __forceinline__ void mfma_v(f32x4& d, v8bf a, v8bf b){
  asm("v_mfma_f32_16x16x32_bf16 %0, %1, %2, %0" : "+v"(d) : "v"(a), "v"(b));
}

// ---- pack W = [W_hh | W_ih] into per-(kt,wave,ct) MFMA B-frags, bf16
__global__ void k_pack_w(const float* __restrict__ Whh, const float* __restrict__ Wih,
                         u16* __restrict__ wpack){
  int idx = blockIdx.x*256 + threadIdx.x;
  if (idx >= 10*SLABE) return;                 // 327680
  int j    = idx & 7;
  int lane = (idx >> 3) & 63;
  int ct   = (idx >> 9) & 7;
  int w    = (idx >> 12) & 7;
  int kt   = idx >> 15;
  int col  = (ct >> 1)*256 + w*32 + (ct & 1)*16 + (lane & 15);
  int k    = kt*32 + (lane >> 4)*8 + j;
  float v  = (k < 256) ? Whh[col*256 + k] : Wih[col*64 + (k - 256)];
  wpack[idx] = f2bf(v);
}

__global__ void k_bias(const float* __restrict__ bi, const float* __restrict__ bh,
                       float* __restrict__ bias){
  int i = blockIdx.x*256 + threadIdx.x;
  if (i < 1024) bias[i] = bi[i] + bh[i];
}

__global__ void k_wlin(const float* __restrict__ Wl, u16* __restrict__ wlin){
  int i = blockIdx.x*256 + threadIdx.x;
  if (i >= 64*264) return;
  int col = i / 264, k = i % 264;
  wlin[i] = (k < 256) ? f2bf(Wl[col*256 + k]) : (u16)0;
}

// ---- x(B,C,F,T) -> y(n,t,c) bf16, n = b*257+f
__global__ void k_ytrans(const float* __restrict__ x, u16* __restrict__ ybuf){
  __shared__ u16 tile[64][257];
  int n = blockIdx.x, b = n / 257, f = n % 257, tid = threadIdx.x;
  for (int i = tid; i < 64*256; i += 256){
    int c = i >> 8, t = i & 255;
    tile[c][t] = f2bf(x[((size_t)(b*64 + c)*257 + f)*256 + t]);
  }
  __syncthreads();
  for (int i = tid; i < 256*64; i += 256){
    int t = i >> 6, c = i & 63;
    ybuf[((size_t)n*256 + t)*64 + c] = tile[c][t];
  }
}

// ---- xg precompute: xg[n,t,:] = y[n,t,:] @ W_ih^T + (b_ih+b_hh), packed in
// acc-fragment layout: xgp[(((g*TT+t)*8+w)*64+lane)*32 + ct*4 + j], bf16
__global__ __launch_bounds__(512) void k_xgates(const u16* __restrict__ wpack,
      const float* __restrict__ bias, const u16* __restrict__ ybuf,
      u16* __restrict__ xgp){
  __shared__ u16 yt[16*16*72];          // [tt][seq][72] (144B row stride)
  const int g = blockIdx.x, t0 = blockIdx.y*16, n0 = g*16;
  const int tid = threadIdx.x, lane = tid & 63, w = tid >> 6;
  const int l15 = lane & 15, q = lane >> 4;

  // W_ih B-frags (kt8,9 of wpack)
  v8bf wf[2][8];
  #pragma unroll
  for (int kf = 0; kf < 2; ++kf)
    #pragma unroll
    for (int ct = 0; ct < 8; ++ct)
      wf[kf][ct] = *(const v8bf*)(wpack + (((8 + kf)*8 + w)*8 + ct)*512 + lane*8);
  float biasr[8];
  #pragma unroll
  for (int ct = 0; ct < 8; ++ct)
    biasr[ct] = bias[(ct >> 1)*256 + w*32 + (ct & 1)*16 + l15];

  // stage y tile: 16 seqs x 16 t x 64 c
  #pragma unroll
  for (int s = 0; s < 4; ++s){
    int i = tid + s*512;
    int seq = i >> 7, tt = (i >> 3) & 15, c8 = i & 7;
    uint4 v = {0u,0u,0u,0u};
    if (n0 + seq < NSEQ)
      v = *(const uint4*)(ybuf + ((size_t)(n0 + seq)*TT + t0 + tt)*64 + c8*8);
    *(uint4*)(yt + tt*1152 + seq*72 + c8*8) = v;
  }
  __syncthreads();

  for (int tt = 0; tt < 16; ++tt){
    f32x4 acc[8];
    #pragma unroll
    for (int ct = 0; ct < 8; ++ct)
      acc[ct] = (f32x4){biasr[ct], biasr[ct], biasr[ct], biasr[ct]};
    v8bf a0 = *(const v8bf*)(yt + tt*1152 + l15*72 + q*8);
    v8bf a1 = *(const v8bf*)(yt + tt*1152 + l15*72 + 32 + q*8);
    #pragma unroll
    for (int ct = 0; ct < 8; ++ct){
      acc[ct] = __builtin_amdgcn_mfma_f32_16x16x32_bf16(a0, wf[0][ct], acc[ct], 0, 0, 0);
      acc[ct] = __builtin_amdgcn_mfma_f32_16x16x32_bf16(a1, wf[1][ct], acc[ct], 0, 0, 0);
    }
    unsigned dw[16];
    #pragma unroll
    for (int ct = 0; ct < 8; ++ct)
      #pragma unroll
      for (int p = 0; p < 2; ++p)
        dw[ct*2 + p] = (unsigned)f2bf(acc[ct][2*p]) | ((unsigned)f2bf(acc[ct][2*p + 1]) << 16);
    u16* dst = xgp + ((((size_t)g*TT + t0 + tt)*8 + w)*64 + lane)*32;
    *(uint4*)(dst +  0) = (uint4){dw[0], dw[1], dw[2], dw[3]};
    *(uint4*)(dst +  8) = (uint4){dw[4], dw[5], dw[6], dw[7]};
    *(uint4*)(dst + 16) = (uint4){dw[8], dw[9], dw[10], dw[11]};
    *(uint4*)(dst + 24) = (uint4){dw[12], dw[13], dw[14], dw[15]};
  }
}

// ---- xg-path LSTM: 65 blocks x 512 thr, K=256 (8 kt).
// kt0..3 AGPR (128/wave), kt4,5 LDS (128 KB), kt6,7 streamed (128 KB/step).
// acc initialized from prefetched xg fragment; no y staging, no bias.
__global__ __launch_bounds__(512, 2) void k_lstm_xg(const u16* __restrict__ wpack,
      const u16* __restrict__ xgp, u16* __restrict__ hbuf){
  extern __shared__ char smem[];
  char* lA = smem;                              // [2][16][AROWX]
  u16*  lW = (u16*)(smem + 2*XG_A);             // kt4,5 slabs
  const int tid = threadIdx.x, lane = tid & 63, w = tid >> 6;
  const int g = blockIdx.x, n0 = g*16;
  const int l15 = lane & 15, q = lane >> 4;
  const int srow = tid >> 5, schunk = tid & 31;

  v8bf wreg[4][8];
  #pragma unroll
  for (int kt = 0; kt < 4; ++kt)
    #pragma unroll
    for (int ct = 0; ct < 8; ++ct)
      wreg[kt][ct] = *(const v8bf*)(wpack + ((kt*8 + w)*8 + ct)*512 + lane*8);

  { // LDS-resident kt4,5
    const uint4* src = (const uint4*)(wpack + 4*SLABE);
    uint4* dst = (uint4*)lW;
    for (int i = tid; i < (2*SLABE)/8; i += 512) dst[i] = src[i];
  }
  { // zero A buffers (h(-1)=0)
    unsigned* z = (unsigned*)lA;
    for (int i = tid; i < (2*XG_A)/4; i += 512) z[i] = 0;
  }
  f32x4 creg[2];
  creg[0] = (f32x4){0.f,0.f,0.f,0.f};
  creg[1] = (f32x4){0.f,0.f,0.f,0.f};
  __syncthreads();

  const u16* wp = wpack;            // opaque-refreshed (defeats LICM/CSE)

  v8bf sbuf[8];
  uint4 xgv[4];
  { // prologue: kt6 for t=0, xg for t=0
    const u16* wpw0 = wp + w*4096 + lane*8;
    #pragma unroll
    for (int ct = 0; ct < 8; ++ct) sbuf[ct] = *(const v8bf*)(wpw0 + 6*SLABE + ct*512);
    const u16* xb = xgp + ((((size_t)g*TT + 0)*8 + w)*64 + lane)*32;
    xgv[0] = *(const uint4*)(xb +  0);
    xgv[1] = *(const uint4*)(xb +  8);
    xgv[2] = *(const uint4*)(xb + 16);
    xgv[3] = *(const uint4*)(xb + 24);
  }

  for (int t = 0; t < TT; ++t){
    char* Acur = lA + (t & 1)*XG_A;
    char* Anxt = lA + ((t + 1) & 1)*XG_A;
    asm("" : "+s"(wp));
    const u16* wpw = wp + w*4096 + lane*8;

    // h(t-1) writeout (overlaps MFMA)
    if (t >= 1 && n0 + srow < NSEQ){
      uint4 hv = *(const uint4*)(Acur + srow*AROWX + schunk*16);
      *(uint4*)(hbuf + ((size_t)(n0 + srow)*TT + (t - 1))*HH + schunk*8) = hv;
    }

    // acc init from xg fragment (bf16 -> f32 by shift)
    f32x4 acc[8];
    #pragma unroll
    for (int ct = 0; ct < 8; ++ct){
      #pragma unroll
      for (int p = 0; p < 2; ++p){
        unsigned u = ((const unsigned*)&xgv[(ct*2 + p) >> 2])[(ct*2 + p) & 3];
        acc[ct][2*p]     = __builtin_bit_cast(float, u << 16);
        acc[ct][2*p + 1] = __builtin_bit_cast(float, u & 0xffff0000u);
      }
    }
    asm volatile("s_nop 1"
      : "+v"(acc[0]), "+v"(acc[1]), "+v"(acc[2]), "+v"(acc[3]),
        "+v"(acc[4]), "+v"(acc[5]), "+v"(acc[6]), "+v"(acc[7]));

    // issue xg(t+1) now (slack = whole step)
    if (t + 1 < TT){
      const u16* xb = xgp + ((((size_t)g*TT + (t + 1))*8 + w)*64 + lane)*32;
      xgv[0] = *(const uint4*)(xb +  0);
      xgv[1] = *(const uint4*)(xb +  8);
      xgv[2] = *(const uint4*)(xb + 16);
      xgv[3] = *(const uint4*)(xb + 24);
    }
    __builtin_amdgcn_sched_barrier(0);

    #define AFRAGX(kt) (*(const v8bf*)(Acur + l15*AROWX + (kt)*64 + q*16))
    #define LFRAGX(kt,ct) (*(const v8bf*)(lW + (((kt)-4)*8 + w)*4096 + (ct)*512 + lane*8))

    { v8bf a = AFRAGX(0);                        // kt0 (AGPR)
      #pragma unroll
      for (int ct = 0; ct < 8; ++ct) mfma_a(acc[ct], a, wreg[0][ct]); }
    { v8bf a = AFRAGX(6);                        // kt6 (loaded prev step) -> refill kt7
      #pragma unroll
      for (int ct = 0; ct < 8; ++ct) mfma_v(acc[ct], a, sbuf[ct]);
      #pragma unroll
      for (int ct = 0; ct < 8; ++ct) sbuf[ct] = *(const v8bf*)(wpw + 7*SLABE + ct*512);
      __builtin_amdgcn_sched_barrier(0); }
    { v8bf a = AFRAGX(1);                        // kt1 (AGPR)
      #pragma unroll
      for (int ct = 0; ct < 8; ++ct) mfma_a(acc[ct], a, wreg[1][ct]); }
    { v8bf a = AFRAGX(2);                        // kt2 (AGPR)
      #pragma unroll
      for (int ct = 0; ct < 8; ++ct) mfma_a(acc[ct], a, wreg[2][ct]); }
    { v8bf a = AFRAGX(3);                        // kt3 (AGPR)
      #pragma unroll
      for (int ct = 0; ct < 8; ++ct) mfma_a(acc[ct], a, wreg[3][ct]); }
    { v8bf a = AFRAGX(4);                        // kt4 (LDS)
      #pragma unroll
      for (int ct = 0; ct < 8; ++ct) mfma_v(acc[ct], a, LFRAGX(4,ct)); }
    { v8bf a = AFRAGX(7);                        // kt7 -> refill kt6 for t+1
      #pragma unroll
      for (int ct = 0; ct < 8; ++ct) mfma_v(acc[ct], a, sbuf[ct]);
      #pragma unroll
      for (int ct = 0; ct < 8; ++ct) sbuf[ct] = *(const v8bf*)(wpw + 6*SLABE + ct*512);
      __builtin_amdgcn_sched_barrier(0); }
    { v8bf a = AFRAGX(5);                        // kt5 (LDS)
      #pragma unroll
      for (int ct = 0; ct < 8; ++ct) mfma_v(acc[ct], a, LFRAGX(5,ct)); }

    // MFMA->VALU hazard guard
    asm volatile("s_nop 7\n\ts_nop 7\n\ts_nop 7"
      : "+v"(acc[0]), "+v"(acc[1]), "+v"(acc[2]), "+v"(acc[3]),
        "+v"(acc[4]), "+v"(acc[5]), "+v"(acc[6]), "+v"(acc[7]));

    // cell update: lane owns units w*32+u*16+l15, rows 4q+j
    #pragma unroll
    for (int u = 0; u < 2; ++u){
      #pragma unroll
      for (int j = 0; j < 4; ++j){
        float xi = acc[0 + u][j], xf = acc[2 + u][j], xg = acc[4 + u][j], xo = acc[6 + u][j];
        float cv = sigm(xf)*creg[u][j] + sigm(xi)*tanh_f(xg);
        float hv = sigm(xo)*tanh_f(cv);
        creg[u][j] = cv;
        int row = 4*q + j, unit = w*32 + u*16 + l15;
        *(u16*)(Anxt + row*AROWX + unit*2) = f2bf(hv);
      }
    }
    __syncthreads();
  }
  { // final h[255] sits in buf (TT&1)=0
    char* Afin = lA + (TT & 1)*XG_A;
    if (n0 + srow < NSEQ){
      uint4 hv = *(const uint4*)(Afin + srow*AROWX + schunk*16);
      *(uint4*)(hbuf + ((size_t)(n0 + srow)*TT + (TT - 1))*HH + schunk*8) = hv;
    }
  }
}

// ---- fallback LSTM (r7 verbatim): used when ws_size can't hold xgp
__global__ __launch_bounds__(512, 2) void k_lstm_fb(const u16* __restrict__ wpack,
      const float* __restrict__ bias, const u16* __restrict__ ybuf,
      u16* __restrict__ hbuf){
  extern __shared__ char smem[];
  char* lA = smem;
  u16*  lW = (u16*)(smem + 2*16*AROWB);
  const int tid = threadIdx.x, lane = tid & 63, w = tid >> 6;
  const int n0 = blockIdx.x * 16;
  const int l15 = lane & 15, q = lane >> 4;
  const int srow = tid >> 5, schunk = tid & 31;

  v8bf wreg[4][8];
  #pragma unroll
  for (int kt = 0; kt < 4; ++kt)
    #pragma unroll
    for (int ct = 0; ct < 8; ++ct)
      wreg[kt][ct] = *(const v8bf*)(wpack + ((kt*8 + w)*8 + ct)*512 + lane*8);
  {
    const uint4* src = (const uint4*)(wpack + 4*SLABE);
    uint4* dst = (uint4*)lW;
    for (int i = tid; i < (2*SLABE)/8; i += 512) dst[i] = src[i];
  }
  float biasr[8];
  #pragma unroll
  for (int ct = 0; ct < 8; ++ct)
    biasr[ct] = bias[(ct >> 1)*256 + w*32 + (ct & 1)*16 + l15];
  {
    unsigned* z = (unsigned*)lA;
    for (int i = tid; i < (2*16*AROWB)/4; i += 512) z[i] = 0;
  }
  __syncthreads();
  {
    unsigned v = 0;
    if (n0 + srow < NSEQ)
      v = *(const unsigned*)(ybuf + ((size_t)(n0 + srow)*TT + 0)*64 + (tid & 31)*2);
    *(unsigned*)(lA + srow*AROWB + 512 + (tid & 31)*4) = v;
  }
  f32x4 creg[2];
  creg[0] = (f32x4){0.f,0.f,0.f,0.f};
  creg[1] = (f32x4){0.f,0.f,0.f,0.f};
  __syncthreads();

  const u16* wp = wpack;
  v8bf sbuf[8];
  {
    const u16* wpw0 = wp + w*4096 + lane*8;
    #pragma unroll
    for (int ct = 0; ct < 8; ++ct) sbuf[ct] = *(const v8bf*)(wpw0 + 6*SLABE + ct*512);
  }

  for (int t = 0; t < TT; ++t){
    char* Acur = lA + (t & 1)*16*AROWB;
    char* Anxt = lA + ((t + 1) & 1)*16*AROWB;
    asm("" : "+s"(wp));
    const u16* wpw = wp + w*4096 + lane*8;

    unsigned yv = 0;
    if (t + 1 < TT && n0 + srow < NSEQ)
      yv = *(const unsigned*)(ybuf + ((size_t)(n0 + srow)*TT + (t + 1))*64 + (tid & 31)*2);

    if (t >= 1 && n0 + srow < NSEQ){
      uint4 hv = *(const uint4*)(Acur + srow*AROWB + schunk*16);
      *(uint4*)(hbuf + ((size_t)(n0 + srow)*TT + (t - 1))*HH + schunk*8) = hv;
    }

    f32x4 acc[8];
    #pragma unroll
    for (int ct = 0; ct < 8; ++ct)
      acc[ct] = (f32x4){biasr[ct], biasr[ct], biasr[ct], biasr[ct]};
    asm volatile("s_nop 1"
      : "+v"(acc[0]), "+v"(acc[1]), "+v"(acc[2]), "+v"(acc[3]),
        "+v"(acc[4]), "+v"(acc[5]), "+v"(acc[6]), "+v"(acc[7]));

    #define AFRAG(kt) (*(const v8bf*)(Acur + l15*AROWB + (kt)*64 + q*16))
    #define LFRAG(kt,ct) (*(const v8bf*)(lW + (((kt)-4)*8 + w)*4096 + (ct)*512 + lane*8))

    { v8bf a = AFRAG(0);
      #pragma unroll
      for (int ct = 0; ct < 8; ++ct) mfma_a(acc[ct], a, wreg[0][ct]); }
    { v8bf a = AFRAG(1);
      #pragma unroll
      for (int ct = 0; ct < 8; ++ct) mfma_a(acc[ct], a, wreg[1][ct]); }
    { v8bf a = AFRAG(6);
      #pragma unroll
      for (int ct = 0; ct < 8; ++ct) mfma_v(acc[ct], a, sbuf[ct]);
      #pragma unroll
      for (int ct = 0; ct < 8; ++ct) sbuf[ct] = *(const v8bf*)(wpw + 7*SLABE + ct*512);
      __builtin_amdgcn_sched_barrier(0); }
    { v8bf a = AFRAG(2);
      #pragma unroll
      for (int ct = 0; ct < 8; ++ct) mfma_a(acc[ct], a, wreg[2][ct]); }
    { v8bf a = AFRAG(3);
      #pragma unroll
      for (int ct = 0; ct < 8; ++ct) mfma_a(acc[ct], a, wreg[3][ct]); }
    { v8bf a = AFRAG(7);
      #pragma unroll
      for (int ct = 0; ct < 8; ++ct) mfma_v(acc[ct], a, sbuf[ct]);
      #pragma unroll
      for (int ct = 0; ct < 8; ++ct) sbuf[ct] = *(const v8bf*)(wpw + 8*SLABE + ct*512);
      __builtin_amdgcn_sched_barrier(0); }
    { v8bf a = AFRAG(4);
      #pragma unroll
      for (int ct = 0; ct < 8; ++ct) mfma_v(acc[ct], a, LFRAG(4,ct)); }
    { v8bf a = AFRAG(8);
      #pragma unroll
      for (int ct = 0; ct < 8; ++ct) mfma_v(acc[ct], a, sbuf[ct]);
      #pragma unroll
      for (int ct = 0; ct < 8; ++ct) sbuf[ct] = *(const v8bf*)(wpw + 9*SLABE + ct*512);
      __builtin_amdgcn_sched_barrier(0); }
    { v8bf a = AFRAG(5);
      #pragma unroll
      for (int ct = 0; ct < 8; ++ct) mfma_v(acc[ct], a, LFRAG(5,ct)); }
    { v8bf a = AFRAG(9);
      #pragma unroll
      for (int ct = 0; ct < 8; ++ct) mfma_v(acc[ct], a, sbuf[ct]);
      #pragma unroll
      for (int ct = 0; ct < 8; ++ct) sbuf[ct] = *(const v8bf*)(wpw + 6*SLABE + ct*512);
      __builtin_amdgcn_sched_barrier(0); }

    asm volatile("s_nop 7\n\ts_nop 7\n\ts_nop 7"
      : "+v"(acc[0]), "+v"(acc[1]), "+v"(acc[2]), "+v"(acc[3]),
        "+v"(acc[4]), "+v"(acc[5]), "+v"(acc[6]), "+v"(acc[7]));

    #pragma unroll
    for (int u = 0; u < 2; ++u){
      #pragma unroll
      for (int j = 0; j < 4; ++j){
        float xi = acc[0 + u][j], xf = acc[2 + u][j], xg = acc[4 + u][j], xo = acc[6 + u][j];
        float cv = sigm(xf)*creg[u][j] + sigm(xi)*tanh_f(xg);
        float hv = sigm(xo)*tanh_f(cv);
        creg[u][j] = cv;
        int row = 4*q + j, unit = w*32 + u*16 + l15;
        *(u16*)(Anxt + row*AROWB + unit*2) = f2bf(hv);
      }
    }
    if (t + 1 < TT)
      *(unsigned*)(Anxt + srow*AROWB + 512 + (tid & 31)*4) = yv;
    __syncthreads();
  }
  {
    char* Afin = lA + (TT & 1)*16*AROWB;
    if (n0 + srow < NSEQ){
      uint4 hv = *(const uint4*)(Afin + srow*AROWB + schunk*16);
      *(uint4*)(hbuf + ((size_t)(n0 + srow)*TT + (TT - 1))*HH + schunk*8) = hv;
    }
  }
}

// ---- out = h @ W_lin^T + b_lin, written as (B,OUT,F,T)
__global__ __launch_bounds__(256) void k_outproj(const u16* __restrict__ hbuf,
      const u16* __restrict__ wlin, const float* __restrict__ blin,
      float* __restrict__ out){
  extern __shared__ char smem[];
  u16* sA = (u16*)smem;
  u16* sB = (u16*)(smem + 128*264*2);
  const int n = blockIdx.x, th = blockIdx.y, t0 = th*128;
  const int b = n / 257, f = n % 257;
  const int tid = threadIdx.x, lane = tid & 63, wv = tid >> 6;

  for (int i = tid; i < 128*32; i += 256){
    int r = i >> 5, part = i & 31;
    *(uint4*)(sA + r*264 + part*8) =
        *(const uint4*)(hbuf + ((size_t)n*TT + t0 + r)*HH + part*8);
  }
  for (int i = tid; i < (64*264)/2; i += 256)
    ((unsigned*)sB)[i] = ((const unsigned*)wlin)[i];
  __syncthreads();

  f32x4 acc[2][4];
  #pragma unroll
  for (int m = 0; m < 2; ++m)
    #pragma unroll
    for (int nt = 0; nt < 4; ++nt){
      float bv = blin[nt*16 + (lane & 15)];
      acc[m][nt] = (f32x4){bv, bv, bv, bv};
    }
  const int khi = (lane >> 4) * 8;
  #pragma unroll
  for (int kt = 0; kt < 8; ++kt){
    v8bf av[2];
    #pragma unroll
    for (int m = 0; m < 2; ++m){
      int mt = wv*2 + m;
      av[m] = *(const v8bf*)(sA + (mt*16 + (lane & 15))*264 + kt*32 + khi);
    }
    #pragma unroll
    for (int nt = 0; nt < 4; ++nt){
      v8bf bv = *(const v8bf*)(sB + (nt*16 + (lane & 15))*264 + kt*32 + khi);
      #pragma unroll
      for (int m = 0; m < 2; ++m)
        acc[m][nt] = __builtin_amdgcn_mfma_f32_16x16x32_bf16(av[m], bv, acc[m][nt], 0, 0, 0);
    }
  }
  #pragma unroll
  for (int m = 0; m < 2; ++m){
    int mt = wv*2 + m;
    #pragma unroll
    for (int nt = 0; nt < 4; ++nt){
      int o = nt*16 + (lane & 15);
      int tb = t0 + mt*16 + 4*(lane >> 4);
      *(f32x4*)(out + (((size_t)b*64 + o)*257 + f)*TT + tb) = acc[m][nt];
    }
  }
}

extern "C" void kernel_launch(void* const* d_in, const int* in_sizes, int n_in,
                              void* d_out, int out_size, void* d_ws, size_t ws_size,
                              hipStream_t stream) {
  const float* x   = (const float*)d_in[0];
  const float* Wih = (const float*)d_in[1];
  const float* Whh = (const float*)d_in[2];
  const float* bih = (const float*)d_in[3];
  const float* bhh = (const float*)d_in[4];
  const float* Wl  = (const float*)d_in[5];
  const float* bl  = (const float*)d_in[6];
  float* out = (float*)d_out;

  char* p = (char*)d_ws;
  u16*   wpack = (u16*)p;   p += 655360;
  float* bias  = (float*)p; p += 4096;
  u16*   wlin  = (u16*)p;   p += 33792;
  u16*   ybuf  = (u16*)p;   p += (size_t)NSEQ*TT*CC*2;   // 33,685,504
  u16*   hbuf  = (u16*)p;   p += (size_t)NSEQ*TT*HH*2;   // 134,742,016
  u16*   xgp   = (u16*)p;
  const size_t XGP_BYTES = (size_t)65*TT*8*64*32*2;      // 545,259,520
  const size_t NEED = (size_t)(p - (char*)d_ws) + XGP_BYTES;

  hipFuncSetAttribute((const void*)k_lstm_xg, hipFuncAttributeMaxDynamicSharedMemorySize, XG_LDS);
  hipFuncSetAttribute((const void*)k_lstm_fb, hipFuncAttributeMaxDynamicSharedMemorySize, FB_LDS);
  hipFuncSetAttribute((const void*)k_outproj, hipFuncAttributeMaxDynamicSharedMemorySize, OUTP_LDS);

  k_pack_w <<<1280, 256, 0, stream>>>(Whh, Wih, wpack);
  k_bias   <<<4,    256, 0, stream>>>(bih, bhh, bias);
  k_wlin   <<<66,   256, 0, stream>>>(Wl, wlin);
  k_ytrans <<<1028, 256, 0, stream>>>(x, ybuf);

  if (ws_size >= NEED) {
    k_xgates <<<dim3(65, 16), 512, 0, stream>>>(wpack, bias, ybuf, xgp);
    k_lstm_xg<<<65, 512, XG_LDS, stream>>>(wpack, xgp, hbuf);
  } else {
    k_lstm_fb<<<65, 512, FB_LDS, stream>>>(wpack, bias, ybuf, hbuf);
  }
  k_outproj<<<dim3(1028, 2), 256, OUTP_LDS, stream>>>(hbuf, wlin, bl, out);
}